// Round 1
// baseline (656.725 us; speedup 1.0000x reference)
//
#include <hip/hip_runtime.h>
#include <math.h>

#define NB   32
#define NA   64
#define EDIM 256
#define HIS  50
#define DKA  9
#define NV   8

// One block per (b,n). 256 threads.
// Phases: A) load q row + one-hot->index   B) gather neighbor actions
//         C) qh = relu(q@Wq), enc = gelu(neigh@Wenc)+PE  -> LDS
//         D) kh GEMM (reg-tiled 13t x 4e per thread) + att logits via shfl
//         E) softmax over t (8 lanes)      F) vh GEMM fused with PV
//         G) out = relu(o@Wout + bout)
__global__ __launch_bounds__(256) void mha_fused(
    const float* __restrict__ q,
    const float* __restrict__ kin,
    const float* __restrict__ adjs,
    const float* __restrict__ Wq, const float* __restrict__ bq,
    const float* __restrict__ Wk, const float* __restrict__ bk,
    const float* __restrict__ Wv, const float* __restrict__ bv,
    const float* __restrict__ Wout, const float* __restrict__ bout,
    const float* __restrict__ Wenc,
    float* __restrict__ out)
{
    const int tid  = threadIdx.x;
    const int bidx = blockIdx.x;
    const int b = bidx >> 6;
    const int n = bidx & 63;

    __shared__ __align__(16) float s_q[EDIM];
    __shared__ __align__(16) float s_qh[EDIM];
    __shared__ __align__(16) float s_neigh[HIS][12];   // 9 used, pad->12, pad zeroed
    __shared__ __align__(16) float s_enc[HIS * EDIM];  // 51200 B
    __shared__ float s_att[NV][66];                    // pad 50->66 (bank spread)
    __shared__ __align__(16) float s_opart[4][EDIM];
    __shared__ __align__(16) float s_o[EDIM];
    __shared__ int s_idx[HIS];

    // ---------- Phase A: q row + one-hot -> neighbor index ----------
    s_q[tid] = q[bidx * EDIM + tid];
    if (tid < HIS) {
        const float* row = adjs + (n * HIS + tid) * NA;
        int best = 0;
        #pragma unroll
        for (int a = 0; a < NA; ++a) best = (row[a] > 0.5f) ? a : best;
        s_idx[tid] = best;
    }
    __syncthreads();

    // ---------- Phase B: gather neighbor actions (zero the pad) ----------
    for (int i = tid; i < HIS * 12; i += 256) {
        const int t = i / 12;
        const int d = i - t * 12;
        float val = 0.0f;
        if (d < DKA) {
            const int a = s_idx[t];
            val = kin[((b * HIS + t) * NA + a) * DKA + d];
        }
        s_neigh[t][d] = val;
    }
    __syncthreads();

    // ---------- Phase C: qh + enc ----------
    {
        const int e = tid;
        float acc = bq[e];
        #pragma unroll 4
        for (int d0 = 0; d0 < EDIM; d0 += 4) {
            const float4 qv = *reinterpret_cast<const float4*>(&s_q[d0]);
            acc += qv.x * Wq[(d0 + 0) * EDIM + e];
            acc += qv.y * Wq[(d0 + 1) * EDIM + e];
            acc += qv.z * Wq[(d0 + 2) * EDIM + e];
            acc += qv.w * Wq[(d0 + 3) * EDIM + e];
        }
        s_qh[e] = fmaxf(acc, 0.0f);

        float we[12];
        #pragma unroll
        for (int j = 0; j < 12; ++j) we[j] = (j < DKA) ? Wenc[j * EDIM + e] : 0.0f;

        // PE: div_term for column pair = exp(-(e & ~1) * ln(10000)/256)
        const float dt = expf(-(float)(e & ~1) * (9.210340371976184f / 256.0f));
        for (int t = 0; t < HIS; ++t) {
            const float4 n0 = *reinterpret_cast<const float4*>(&s_neigh[t][0]);
            const float4 n1 = *reinterpret_cast<const float4*>(&s_neigh[t][4]);
            const float4 n2 = *reinterpret_cast<const float4*>(&s_neigh[t][8]);
            float x = n0.x*we[0] + n0.y*we[1] + n0.z*we[2] + n0.w*we[3]
                    + n1.x*we[4] + n1.y*we[5] + n1.z*we[6] + n1.w*we[7]
                    + n2.x*we[8];
            // exact GELU
            x = 0.5f * x * (1.0f + erff(x * 0.70710678118654752f));
            const float arg = (float)t * dt;
            const float pe = (e & 1) ? cosf(arg) : sinf(arg);
            s_enc[t * EDIM + e] = x + pe;
        }
    }
    __syncthreads();

    // thread -> (4 e-columns, 13 t-rows) tiling for the two big GEMMs
    const int g = tid & 63;         // e-group: columns 4g..4g+3
    const int h = tid >> 6;         // wave id -> t-quarter
    const int tbase  = (h == 0) ? 0 : (h == 1) ? 13 : (h == 2) ? 25 : 37;
    const int tcount = (h == 1 || h == 2) ? 12 : 13;   // disjoint cover of 50
    const int v = g >> 3;           // head of my columns (4g+j)>>5 == g>>3

    // ---------- Phase D: kh GEMM + att logits ----------
    {
        float4 kacc[13];
        const float4 bkv = *reinterpret_cast<const float4*>(&bk[4 * g]);
        #pragma unroll
        for (int tt = 0; tt < 13; ++tt) kacc[tt] = bkv;

        #pragma unroll 2
        for (int d0 = 0; d0 < EDIM; d0 += 4) {
            const float4 w0 = *reinterpret_cast<const float4*>(&Wk[(d0 + 0) * EDIM + 4 * g]);
            const float4 w1 = *reinterpret_cast<const float4*>(&Wk[(d0 + 1) * EDIM + 4 * g]);
            const float4 w2 = *reinterpret_cast<const float4*>(&Wk[(d0 + 2) * EDIM + 4 * g]);
            const float4 w3 = *reinterpret_cast<const float4*>(&Wk[(d0 + 3) * EDIM + 4 * g]);
            #pragma unroll
            for (int tt = 0; tt < 13; ++tt) {
                const float4 ev = *reinterpret_cast<const float4*>(&s_enc[(tbase + tt) * EDIM + d0]);
                kacc[tt].x += ev.x * w0.x + ev.y * w1.x + ev.z * w2.x + ev.w * w3.x;
                kacc[tt].y += ev.x * w0.y + ev.y * w1.y + ev.z * w2.y + ev.w * w3.y;
                kacc[tt].z += ev.x * w0.z + ev.y * w1.z + ev.z * w2.z + ev.w * w3.z;
                kacc[tt].w += ev.x * w0.w + ev.y * w1.w + ev.z * w2.w + ev.w * w3.w;
            }
        }

        const float4 qv = *reinterpret_cast<const float4*>(&s_qh[4 * g]);
        #pragma unroll
        for (int tt = 0; tt < 13; ++tt) {
            float p = qv.x * fmaxf(kacc[tt].x, 0.0f)
                    + qv.y * fmaxf(kacc[tt].y, 0.0f)
                    + qv.z * fmaxf(kacc[tt].z, 0.0f)
                    + qv.w * fmaxf(kacc[tt].w, 0.0f);
            // reduce over the 8 lanes (g within octet) holding head v
            p += __shfl_xor(p, 1);
            p += __shfl_xor(p, 2);
            p += __shfl_xor(p, 4);
            if ((g & 7) == 0) s_att[v][tbase + tt] = p * (1.0f / 3.0f);  // /sqrt(9)
        }
    }
    __syncthreads();

    // ---------- Phase E: softmax over t, one lane per head ----------
    if (tid < NV) {
        float m = -1e30f;
        for (int t = 0; t < HIS; ++t) m = fmaxf(m, s_att[tid][t]);
        float ssum = 0.0f;
        for (int t = 0; t < HIS; ++t) {
            const float ex = expf(s_att[tid][t] - m);
            s_att[tid][t] = ex;
            ssum += ex;
        }
        const float inv = 1.0f / ssum;
        for (int t = 0; t < HIS; ++t) s_att[tid][t] *= inv;
    }
    __syncthreads();

    // ---------- Phase F: vh GEMM fused with PV ----------
    {
        float4 vacc[13];
        const float4 bvv = *reinterpret_cast<const float4*>(&bv[4 * g]);
        #pragma unroll
        for (int tt = 0; tt < 13; ++tt) vacc[tt] = bvv;

        #pragma unroll 2
        for (int d0 = 0; d0 < EDIM; d0 += 4) {
            const float4 w0 = *reinterpret_cast<const float4*>(&Wv[(d0 + 0) * EDIM + 4 * g]);
            const float4 w1 = *reinterpret_cast<const float4*>(&Wv[(d0 + 1) * EDIM + 4 * g]);
            const float4 w2 = *reinterpret_cast<const float4*>(&Wv[(d0 + 2) * EDIM + 4 * g]);
            const float4 w3 = *reinterpret_cast<const float4*>(&Wv[(d0 + 3) * EDIM + 4 * g]);
            #pragma unroll
            for (int tt = 0; tt < 13; ++tt) {
                const float4 ev = *reinterpret_cast<const float4*>(&s_enc[(tbase + tt) * EDIM + d0]);
                vacc[tt].x += ev.x * w0.x + ev.y * w1.x + ev.z * w2.x + ev.w * w3.x;
                vacc[tt].y += ev.x * w0.y + ev.y * w1.y + ev.z * w2.y + ev.w * w3.y;
                vacc[tt].z += ev.x * w0.z + ev.y * w1.z + ev.z * w2.z + ev.w * w3.z;
                vacc[tt].w += ev.x * w0.w + ev.y * w1.w + ev.z * w2.w + ev.w * w3.w;
            }
        }

        float4 po = make_float4(0.0f, 0.0f, 0.0f, 0.0f);
        #pragma unroll
        for (int tt = 0; tt < 13; ++tt) {
            if (tt < tcount) {          // disjoint t cover (no double count)
                const float a = s_att[v][tbase + tt];
                po.x += a * fmaxf(vacc[tt].x, 0.0f);
                po.y += a * fmaxf(vacc[tt].y, 0.0f);
                po.z += a * fmaxf(vacc[tt].z, 0.0f);
                po.w += a * fmaxf(vacc[tt].w, 0.0f);
            }
        }
        *reinterpret_cast<float4*>(&s_opart[h][4 * g]) = po;
    }
    __syncthreads();

    s_o[tid] = s_opart[0][tid] + s_opart[1][tid] + s_opart[2][tid] + s_opart[3][tid];
    __syncthreads();

    // ---------- Phase G: out projection ----------
    {
        const int e = tid;
        float acc = bout[e];
        #pragma unroll 4
        for (int d0 = 0; d0 < EDIM; d0 += 4) {
            const float4 ov = *reinterpret_cast<const float4*>(&s_o[d0]);
            acc += ov.x * Wout[(d0 + 0) * EDIM + e];
            acc += ov.y * Wout[(d0 + 1) * EDIM + e];
            acc += ov.z * Wout[(d0 + 2) * EDIM + e];
            acc += ov.w * Wout[(d0 + 3) * EDIM + e];
        }
        out[bidx * EDIM + e] = fmaxf(acc, 0.0f);
    }
}

extern "C" void kernel_launch(void* const* d_in, const int* in_sizes, int n_in,
                              void* d_out, int out_size, void* d_ws, size_t ws_size,
                              hipStream_t stream) {
    const float* q    = (const float*)d_in[0];
    const float* kin  = (const float*)d_in[1];
    const float* adjs = (const float*)d_in[2];
    const float* Wq   = (const float*)d_in[3];
    const float* bq   = (const float*)d_in[4];
    const float* Wk   = (const float*)d_in[5];
    const float* bk   = (const float*)d_in[6];
    const float* Wv   = (const float*)d_in[7];
    const float* bv   = (const float*)d_in[8];
    const float* Wout = (const float*)d_in[9];
    const float* bout = (const float*)d_in[10];
    const float* Wenc = (const float*)d_in[11];
    float* out = (float*)d_out;

    dim3 grid(NB * NA);
    dim3 block(256);
    hipLaunchKernelGGL(mha_fused, grid, block, 0, stream,
                       q, kin, adjs, Wq, bq, Wk, bk, Wv, bv, Wout, bout, Wenc, out);
}

// Round 2
// 219.286 us; speedup vs baseline: 2.9948x; 2.9948x over previous
//
#include <hip/hip_runtime.h>
#include <math.h>

#define NB   32
#define NA   64
#define EDIM 256
#define HIS  50
#define DKA  9
#define NV   8

typedef _Float16 HALF;
typedef _Float16 half8 __attribute__((ext_vector_type(8)));
typedef float    f32x4 __attribute__((ext_vector_type(4)));

// ws layout (bytes):
//   0       WkP  f16 packed   131072   (fragment order)
//   131072  WvP  f16 packed   131072
//   262144  WqT  f16 [e][d]   131072
//   393216  WoutT f16 [e][d]  131072
//   524288  PE   f32 [50][256] 51200
#define WS_WKP   0
#define WS_WVP   131072
#define WS_WQT   262144
#define WS_WOUT  393216
#define WS_PE    524288

// ---------------- setup: pack weights to f16, precompute PE ----------------
__global__ __launch_bounds__(256) void pack_setup(
    const float* __restrict__ Wk, const float* __restrict__ Wv,
    const float* __restrict__ Wq, const float* __restrict__ Wout,
    char* __restrict__ ws)
{
    const int tid = blockIdx.x * 256 + threadIdx.x;   // 0..65535
    HALF* WkP  = (HALF*)(ws + WS_WKP);
    HALF* WvP  = (HALF*)(ws + WS_WVP);
    HALF* WqT  = (HALF*)(ws + WS_WQT);
    HALF* WoT  = (HALF*)(ws + WS_WOUT);
    float* PE  = (float*)(ws + WS_PE);

    // fragment pack: out = ((ntile*8 + ktile)*64 + lane)*8 + elem
    // lane: (k>>3)&3 -> lane>>4 ; n&15 -> lane&15 ; elem = k&7
    {
        const int elem = tid & 7;
        const int lane = (tid >> 3) & 63;
        const int kt   = (tid >> 9) & 7;
        const int nt   = tid >> 12;
        const int k = kt * 32 + (lane >> 4) * 8 + elem;
        const int n = nt * 16 + (lane & 15);
        WkP[tid] = (HALF)Wk[k * EDIM + n];
        WvP[tid] = (HALF)Wv[k * EDIM + n];
    }
    // transposes for the matvecs
    {
        const int d = tid & 255;
        const int e = tid >> 8;
        WqT[tid] = (HALF)Wq[d * EDIM + e];
        WoT[tid] = (HALF)Wout[d * EDIM + e];
    }
    // positional encoding table
    if (tid < HIS * EDIM) {
        const int t = tid >> 8;
        const int e = tid & 255;
        const float dt = expf(-(float)(e & ~1) * (9.210340371976184f / 256.0f));
        const float arg = (float)t * dt;
        PE[tid] = (e & 1) ? cosf(arg) : sinf(arg);
    }
}

// ---------------- main fused kernel: one block per (b,n) ----------------
__global__ __launch_bounds__(256) void mha_mfma(
    const float* __restrict__ q,
    const float* __restrict__ kin,
    const float* __restrict__ adjs,
    const float* __restrict__ bq,
    const float* __restrict__ bk,
    const float* __restrict__ bv,
    const float* __restrict__ bout,
    const float* __restrict__ Wenc,
    const char*  __restrict__ ws,
    float* __restrict__ out)
{
    const int tid  = threadIdx.x;
    const int bidx = blockIdx.x;
    const int b = bidx >> 6;
    const int n = bidx & 63;
    const int lane = tid & 63;
    const int w    = tid >> 6;          // wave id 0..3
    const int l15  = lane & 15;
    const int l4   = lane >> 4;

    const HALF*  WkP = (const HALF*)(ws + WS_WKP);
    const HALF*  WvP = (const HALF*)(ws + WS_WVP);
    const HALF*  WqT = (const HALF*)(ws + WS_WQT);
    const HALF*  WoT = (const HALF*)(ws + WS_WOUT);
    const float* PE  = (const float*)(ws + WS_PE);

    __shared__ __align__(16) float s_q[EDIM];
    __shared__ __align__(16) float s_qh[EDIM];
    __shared__ __align__(16) float s_neigh[HIS][12];   // 9 used, pad zeroed
    __shared__ __align__(16) HALF  s_enc[64 * EDIM];   // swizzled, 32 KB
    __shared__ float s_att[NV][64];
    __shared__ __align__(16) float s_o[EDIM];
    __shared__ int s_idx[HIS];

    // ---------- A: q row + one-hot -> index ----------
    s_q[tid] = q[bidx * EDIM + tid];
    if (tid < HIS) {
        const float* row = adjs + (n * HIS + tid) * NA;
        int best = 0;
        #pragma unroll
        for (int a = 0; a < NA; ++a) best = (row[a] > 0.5f) ? a : best;
        s_idx[tid] = best;
    }
    __syncthreads();

    // ---------- B: gather neighbor actions ----------
    for (int i = tid; i < HIS * 12; i += 256) {
        const int t = i / 12;
        const int d = i - t * 12;
        float val = 0.0f;
        if (d < DKA) val = kin[((b * HIS + t) * NA + s_idx[t]) * DKA + d];
        s_neigh[t][d] = val;
    }
    __syncthreads();

    // ---------- C: qh (f16 matvec) + enc -> f16 LDS (swizzled) ----------
    {
        const int e = tid;
        float acc = bq[e];
        const half8* wq = (const half8*)(WqT + e * EDIM);
        #pragma unroll 4
        for (int d0 = 0; d0 < EDIM; d0 += 8) {
            const half8 hv = wq[d0 >> 3];
            #pragma unroll
            for (int j = 0; j < 8; ++j) acc += s_q[d0 + j] * (float)hv[j];
        }
        s_qh[e] = fmaxf(acc, 0.0f);

        float we[12];
        #pragma unroll
        for (int j = 0; j < 12; ++j) we[j] = (j < DKA) ? Wenc[j * EDIM + e] : 0.0f;

        #pragma unroll 2
        for (int t = 0; t < HIS; ++t) {
            const float4 n0 = *reinterpret_cast<const float4*>(&s_neigh[t][0]);
            const float4 n1 = *reinterpret_cast<const float4*>(&s_neigh[t][4]);
            const float4 n2 = *reinterpret_cast<const float4*>(&s_neigh[t][8]);
            float x = n0.x*we[0] + n0.y*we[1] + n0.z*we[2] + n0.w*we[3]
                    + n1.x*we[4] + n1.y*we[5] + n1.z*we[6] + n1.w*we[7]
                    + n2.x*we[8];
            x = 0.5f * x * (1.0f + erff(x * 0.70710678118654752f));
            const float v = x + PE[t * EDIM + e];
            // swizzled store: half idx = t*256 + ((e>>3)^(t&7))*8 + (e&7)
            s_enc[t * EDIM + (((e >> 3) ^ (t & 7)) << 3) + (e & 7)] = (HALF)v;
        }
        #pragma unroll
        for (int t = HIS; t < 64; ++t)
            s_enc[t * EDIM + (((e >> 3) ^ (t & 7)) << 3) + (e & 7)] = (HALF)0.0f;
    }
    __syncthreads();

    // ---------- D: dual GEMM kh & vh via MFMA ----------
    // wave w owns output cols [64w, 64w+64) = heads 2w, 2w+1
    f32x4 ka[4][4], va[4][4];
    #pragma unroll
    for (int mt = 0; mt < 4; ++mt)
        #pragma unroll
        for (int nt = 0; nt < 4; ++nt) { ka[mt][nt] = (f32x4)0.0f; va[mt][nt] = (f32x4)0.0f; }

    #pragma unroll 2
    for (int kk = 0; kk < 8; ++kk) {
        half8 afr[4];
        #pragma unroll
        for (int mt = 0; mt < 4; ++mt) {
            const int t  = mt * 16 + l15;
            const int g  = ((kk * 4 + l4)) ^ (t & 7);   // granule swizzle
            afr[mt] = *reinterpret_cast<const half8*>(&s_enc[t * EDIM + g * 8]);
        }
        half8 bkfr[4], bvfr[4];
        #pragma unroll
        for (int nt = 0; nt < 4; ++nt) {
            const size_t off = ((size_t)((w * 4 + nt) * 8 + kk) * 64 + lane) * 8;
            bkfr[nt] = *reinterpret_cast<const half8*>(WkP + off);
            bvfr[nt] = *reinterpret_cast<const half8*>(WvP + off);
        }
        #pragma unroll
        for (int mt = 0; mt < 4; ++mt)
            #pragma unroll
            for (int nt = 0; nt < 4; ++nt) {
                ka[mt][nt] = __builtin_amdgcn_mfma_f32_16x16x32_f16(afr[mt], bkfr[nt], ka[mt][nt], 0, 0, 0);
                va[mt][nt] = __builtin_amdgcn_mfma_f32_16x16x32_f16(afr[mt], bvfr[nt], va[mt][nt], 0, 0, 0);
            }
    }

    // ---------- att logits from kh accumulators ----------
    // C/D layout: col = lane&15 (n within tile), row = (lane>>4)*4 + r (t within tile)
    {
        float qv[4], bkb[4];
        #pragma unroll
        for (int nt = 0; nt < 4; ++nt) {
            const int col = w * 64 + nt * 16 + l15;
            qv[nt]  = s_qh[col];
            bkb[nt] = bk[col];
        }
        #pragma unroll
        for (int mt = 0; mt < 4; ++mt)
            #pragma unroll
            for (int r = 0; r < 4; ++r) {
                float p0 = qv[0] * fmaxf(ka[mt][0][r] + bkb[0], 0.0f)
                         + qv[1] * fmaxf(ka[mt][1][r] + bkb[1], 0.0f);
                float p1 = qv[2] * fmaxf(ka[mt][2][r] + bkb[2], 0.0f)
                         + qv[3] * fmaxf(ka[mt][3][r] + bkb[3], 0.0f);
                p0 += __shfl_xor(p0, 1);  p1 += __shfl_xor(p1, 1);
                p0 += __shfl_xor(p0, 2);  p1 += __shfl_xor(p1, 2);
                p0 += __shfl_xor(p0, 4);  p1 += __shfl_xor(p1, 4);
                p0 += __shfl_xor(p0, 8);  p1 += __shfl_xor(p1, 8);
                if (l15 == 0) {
                    const int t = mt * 16 + l4 * 4 + r;
                    s_att[2 * w][t]     = p0 * (1.0f / 3.0f);
                    s_att[2 * w + 1][t] = p1 * (1.0f / 3.0f);
                }
            }
    }
    __syncthreads();

    // ---------- E: softmax over t (one thread per head) ----------
    if (tid < NV) {
        float m = -1e30f;
        for (int t = 0; t < HIS; ++t) m = fmaxf(m, s_att[tid][t]);
        float ssum = 0.0f;
        for (int t = 0; t < HIS; ++t) {
            const float ex = expf(s_att[tid][t] - m);
            s_att[tid][t] = ex;
            ssum += ex;
        }
        const float inv = 1.0f / ssum;
        for (int t = 0; t < HIS; ++t) s_att[tid][t] *= inv;
        for (int t = HIS; t < 64; ++t) s_att[tid][t] = 0.0f;   // kill pad rows
    }
    __syncthreads();

    // ---------- F: PV from vh accumulators ----------
    {
        float bvb[4];
        #pragma unroll
        for (int nt = 0; nt < 4; ++nt) bvb[nt] = bv[w * 64 + nt * 16 + l15];
        float o0 = 0.f, o1 = 0.f, o2 = 0.f, o3 = 0.f;
        #pragma unroll
        for (int mt = 0; mt < 4; ++mt)
            #pragma unroll
            for (int r = 0; r < 4; ++r) {
                const int t = mt * 16 + l4 * 4 + r;
                const float a0 = s_att[2 * w][t];
                const float a1 = s_att[2 * w + 1][t];
                o0 += a0 * fmaxf(va[mt][0][r] + bvb[0], 0.0f);
                o1 += a0 * fmaxf(va[mt][1][r] + bvb[1], 0.0f);
                o2 += a1 * fmaxf(va[mt][2][r] + bvb[2], 0.0f);
                o3 += a1 * fmaxf(va[mt][3][r] + bvb[3], 0.0f);
            }
        o0 += __shfl_xor(o0, 16); o1 += __shfl_xor(o1, 16);
        o2 += __shfl_xor(o2, 16); o3 += __shfl_xor(o3, 16);
        o0 += __shfl_xor(o0, 32); o1 += __shfl_xor(o1, 32);
        o2 += __shfl_xor(o2, 32); o3 += __shfl_xor(o3, 32);
        if (lane < 16) {
            s_o[w * 64 +  0 + l15] = o0;
            s_o[w * 64 + 16 + l15] = o1;
            s_o[w * 64 + 32 + l15] = o2;
            s_o[w * 64 + 48 + l15] = o3;
        }
    }
    __syncthreads();

    // ---------- G: out projection (f16 matvec) ----------
    {
        const int e = tid;
        float acc = bout[e];
        const half8* wo = (const half8*)(WoT + e * EDIM);
        #pragma unroll 4
        for (int d0 = 0; d0 < EDIM; d0 += 8) {
            const half8 hv = wo[d0 >> 3];
            #pragma unroll
            for (int j = 0; j < 8; ++j) acc += s_o[d0 + j] * (float)hv[j];
        }
        out[bidx * EDIM + e] = fmaxf(acc, 0.0f);
    }
}

extern "C" void kernel_launch(void* const* d_in, const int* in_sizes, int n_in,
                              void* d_out, int out_size, void* d_ws, size_t ws_size,
                              hipStream_t stream) {
    const float* q    = (const float*)d_in[0];
    const float* kin  = (const float*)d_in[1];
    const float* adjs = (const float*)d_in[2];
    const float* Wq   = (const float*)d_in[3];
    const float* bq   = (const float*)d_in[4];
    const float* Wk   = (const float*)d_in[5];
    const float* bk   = (const float*)d_in[6];
    const float* Wv   = (const float*)d_in[7];
    const float* bv   = (const float*)d_in[8];
    const float* Wout = (const float*)d_in[9];
    const float* bout = (const float*)d_in[10];
    const float* Wenc = (const float*)d_in[11];
    float* out = (float*)d_out;
    char* ws = (char*)d_ws;

    hipLaunchKernelGGL(pack_setup, dim3(256), dim3(256), 0, stream,
                       Wk, Wv, Wq, Wout, ws);
    hipLaunchKernelGGL(mha_mfma, dim3(NB * NA), dim3(256), 0, stream,
                       q, kin, adjs, bq, bk, bv, bout, Wenc, ws, out);
}

// Round 3
// 122.992 us; speedup vs baseline: 5.3396x; 1.7829x over previous
//
#include <hip/hip_runtime.h>
#include <math.h>

#define NB   32
#define NA   64
#define EDIM 256
#define HIS  50
#define DKA  9
#define NV   8

typedef _Float16 HALF;
typedef _Float16 half4 __attribute__((ext_vector_type(4)));
typedef _Float16 half8 __attribute__((ext_vector_type(8)));
typedef float    f32x4 __attribute__((ext_vector_type(4)));

// ws layout (bytes):
#define WS_WKP   0          // f16 fragment-packed Wk      131072
#define WS_WVP   131072     // f16 fragment-packed Wv      131072
#define WS_WQI   262144     // f16 interleaved WqT [(d>>3)][e][d&7] 131072
#define WS_WOI   393216     // f16 interleaved WoutT       131072
#define WS_PE    524288     // f32 PE [50][256]            51200
#define WS_IDX   575488     // int idxTab [64][50]         12800
#define WS_QH    588288     // f16 qh [2048][256]          1048576
#define WS_ENC   1636864    // f16 enc [2048][50][256] swizzled  52428800
#define WS_NEED  54065664ULL

// ---------------- setup: pack weights, PE table, adjacency index ----------------
__global__ __launch_bounds__(256) void pack_setup(
    const float* __restrict__ Wk, const float* __restrict__ Wv,
    const float* __restrict__ Wq, const float* __restrict__ Wout,
    const float* __restrict__ adjs,
    char* __restrict__ ws)
{
    const int tid = blockIdx.x * 256 + threadIdx.x;   // 0..65535
    HALF* WkP  = (HALF*)(ws + WS_WKP);
    HALF* WvP  = (HALF*)(ws + WS_WVP);
    HALF* WqI  = (HALF*)(ws + WS_WQI);
    HALF* WoI  = (HALF*)(ws + WS_WOI);
    float* PE  = (float*)(ws + WS_PE);
    int*  idxT = (int*)(ws + WS_IDX);

    // B-fragment pack: out = ((ntile*8 + ktile)*64 + lane)*8 + elem
    {
        const int elem = tid & 7;
        const int lane = (tid >> 3) & 63;
        const int kt   = (tid >> 9) & 7;
        const int nt   = tid >> 12;
        const int k = kt * 32 + (lane >> 4) * 8 + elem;
        const int n = nt * 16 + (lane & 15);
        WkP[tid] = (HALF)Wk[k * EDIM + n];
        WvP[tid] = (HALF)Wv[k * EDIM + n];
    }
    // interleaved transposes for coalesced matvec: [(d>>3)][e][d&7]
    {
        const int d = tid & 255;
        const int e = tid >> 8;
        const int dst = ((d >> 3) * EDIM + e) * 8 + (d & 7);
        WqI[dst] = (HALF)Wq[d * EDIM + e];
        WoI[dst] = (HALF)Wout[d * EDIM + e];
    }
    // positional encoding table
    if (tid < HIS * EDIM) {
        const int t = tid >> 8;
        const int e = tid & 255;
        const float dt = expf(-(float)(e & ~1) * (9.210340371976184f / 256.0f));
        const float arg = (float)t * dt;
        PE[tid] = (e & 1) ? cosf(arg) : sinf(arg);
    }
    // adjacency one-hot -> index
    if (tid < NA * HIS) {
        const float* row = adjs + tid * NA;   // tid = n*HIS + t
        int best = 0;
        #pragma unroll
        for (int a = 0; a < NA; ++a) best = (row[a] > 0.5f) ? a : best;
        idxT[tid] = best;
    }
}

// ---------------- K1: enc (pre-swizzled f16) + qh, all (b,n) ----------------
__global__ __launch_bounds__(256) void enc_kernel(
    const float* __restrict__ q,
    const float* __restrict__ kin,
    const float* __restrict__ bq,
    const float* __restrict__ Wenc,
    const char*  __restrict__ ws,
    char* __restrict__ wsout)
{
    const int tid  = threadIdx.x;
    const int bidx = blockIdx.x;
    const int b = bidx >> 6;
    const int n = bidx & 63;
    const int lane = tid & 63;
    const int w    = tid >> 6;

    const HALF* WqI = (const HALF*)(ws + WS_WQI);
    const float* PE = (const float*)(ws + WS_PE);
    const int* idxT = (const int*)(ws + WS_IDX);
    HALF* qh  = (HALF*)(wsout + WS_QH);
    HALF* enc = (HALF*)(wsout + WS_ENC);

    __shared__ __align__(16) float s_q[EDIM];
    __shared__ __align__(16) float s_neigh[HIS][12];

    s_q[tid] = q[bidx * EDIM + tid];
    for (int i = tid; i < HIS * 12; i += 256) {
        const int t = i / 12;
        const int d = i - t * 12;
        float val = 0.0f;
        if (d < DKA) val = kin[((b * HIS + t) * NA + idxT[n * HIS + t]) * DKA + d];
        s_neigh[t][d] = val;
    }
    __syncthreads();

    // qh matvec (coalesced interleaved weights)
    {
        const int e = tid;
        float acc = bq[e];
        #pragma unroll 4
        for (int j = 0; j < 32; ++j) {
            const half8 hv = *reinterpret_cast<const half8*>(&WqI[(j * EDIM + e) * 8]);
            const float4 q0 = *reinterpret_cast<const float4*>(&s_q[j * 8]);
            const float4 q1 = *reinterpret_cast<const float4*>(&s_q[j * 8 + 4]);
            acc += q0.x*(float)hv[0] + q0.y*(float)hv[1] + q0.z*(float)hv[2] + q0.w*(float)hv[3]
                 + q1.x*(float)hv[4] + q1.y*(float)hv[5] + q1.z*(float)hv[6] + q1.w*(float)hv[7];
        }
        qh[bidx * EDIM + e] = (HALF)fmaxf(acc, 0.0f);
    }

    // enc rows: wave w handles t = w, w+4, ...; lane owns e = lane*4 .. +3
    {
        const int e0 = lane * 4;
        float4 we[9];
        #pragma unroll
        for (int d = 0; d < DKA; ++d)
            we[d] = *reinterpret_cast<const float4*>(&Wenc[d * EDIM + e0]);

        for (int t = w; t < HIS; t += 4) {
            const float4 pe = *reinterpret_cast<const float4*>(&PE[t * EDIM + e0]);
            const float4 n0 = *reinterpret_cast<const float4*>(&s_neigh[t][0]);
            const float4 n1 = *reinterpret_cast<const float4*>(&s_neigh[t][4]);
            const float  n8 = s_neigh[t][8];
            float4 x;
            x  = n0.x * we[0];  x += n0.y * we[1];  x += n0.z * we[2];  x += n0.w * we[3];
            x += n1.x * we[4];  x += n1.y * we[5];  x += n1.z * we[6];  x += n1.w * we[7];
            x += n8   * we[8];
            float4 r;
            r.x = 0.5f * x.x * (1.0f + erff(x.x * 0.70710678118654752f)) + pe.x;
            r.y = 0.5f * x.y * (1.0f + erff(x.y * 0.70710678118654752f)) + pe.y;
            r.z = 0.5f * x.z * (1.0f + erff(x.z * 0.70710678118654752f)) + pe.z;
            r.w = 0.5f * x.w * (1.0f + erff(x.w * 0.70710678118654752f)) + pe.w;
            half4 h; h[0] = (HALF)r.x; h[1] = (HALF)r.y; h[2] = (HALF)r.z; h[3] = (HALF)r.w;
            // swizzled store: granule (lane>>1)^(t&7), half-granule lane&1
            const size_t off = (size_t)bidx * (HIS * EDIM) + t * EDIM
                             + (((lane >> 1) ^ (t & 7)) << 3) + ((lane & 1) << 2);
            *reinterpret_cast<half4*>(&enc[off]) = h;
        }
    }
}

// ---------------- K2: attention per (b,n) ----------------
__global__ __launch_bounds__(256) void attn_kernel(
    const float* __restrict__ bk,
    const float* __restrict__ bv,
    const float* __restrict__ bout,
    const char*  __restrict__ ws,
    float* __restrict__ out)
{
    const int tid  = threadIdx.x;
    const int bidx = blockIdx.x;
    const int lane = tid & 63;
    const int w    = tid >> 6;
    const int l15  = lane & 15;
    const int l4   = lane >> 4;

    const HALF* WkP = (const HALF*)(ws + WS_WKP);
    const HALF* WvP = (const HALF*)(ws + WS_WVP);
    const HALF* WoI = (const HALF*)(ws + WS_WOI);
    const HALF* qh  = (const HALF*)(ws + WS_QH);
    const HALF* enc = (const HALF*)(ws + WS_ENC);

    __shared__ __align__(16) HALF s_enc[64 * EDIM];   // 32 KB, swizzled rows
    __shared__ __align__(16) float s_qh[EDIM];
    __shared__ float s_att[NV][64];
    __shared__ __align__(16) float s_o[EDIM];

    // stage enc tile (linear copy of pre-swizzled data) + qh
    s_qh[tid] = (float)qh[bidx * EDIM + tid];
    {
        const half8* src = reinterpret_cast<const half8*>(enc + (size_t)bidx * (HIS * EDIM));
        half8* dst = reinterpret_cast<half8*>(s_enc);
        #pragma unroll
        for (int j = 0; j < 7; ++j) {
            const int idx = j * 256 + tid;
            if (idx < HIS * 32) dst[idx] = src[idx];
        }
        const half8 z = (half8)(HALF)0.0f;
        #pragma unroll
        for (int j = 0; j < 2; ++j) {
            const int idx = HIS * 32 + j * 256 + tid;
            if (idx < 64 * 32) dst[idx] = z;
        }
    }
    __syncthreads();

    // ---- pass 1: kh GEMM -> att logits ----
    f32x4 acc[4][4];
    #pragma unroll
    for (int mt = 0; mt < 4; ++mt)
        #pragma unroll
        for (int nt = 0; nt < 4; ++nt) acc[mt][nt] = (f32x4)0.0f;

    const half8* encv = reinterpret_cast<const half8*>(s_enc);
    #pragma unroll 2
    for (int kk = 0; kk < 8; ++kk) {
        half8 afr[4];
        #pragma unroll
        for (int mt = 0; mt < 4; ++mt) {
            const int t = mt * 16 + l15;
            const int g = (kk * 4 + l4) ^ (t & 7);
            afr[mt] = encv[t * 32 + g];
        }
        #pragma unroll
        for (int nt = 0; nt < 4; ++nt) {
            const half8 bfr = *reinterpret_cast<const half8*>(
                WkP + ((size_t)((w * 4 + nt) * 8 + kk) * 64 + lane) * 8);
            #pragma unroll
            for (int mt = 0; mt < 4; ++mt)
                acc[mt][nt] = __builtin_amdgcn_mfma_f32_16x16x32_f16(afr[mt], bfr, acc[mt][nt], 0, 0, 0);
        }
    }

    {
        float qv[4], bkb[4];
        #pragma unroll
        for (int nt = 0; nt < 4; ++nt) {
            const int col = w * 64 + nt * 16 + l15;
            qv[nt]  = s_qh[col];
            bkb[nt] = bk[col];
        }
        #pragma unroll
        for (int mt = 0; mt < 4; ++mt)
            #pragma unroll
            for (int r = 0; r < 4; ++r) {
                float p0 = qv[0] * fmaxf(acc[mt][0][r] + bkb[0], 0.0f)
                         + qv[1] * fmaxf(acc[mt][1][r] + bkb[1], 0.0f);
                float p1 = qv[2] * fmaxf(acc[mt][2][r] + bkb[2], 0.0f)
                         + qv[3] * fmaxf(acc[mt][3][r] + bkb[3], 0.0f);
                p0 += __shfl_xor(p0, 1);  p1 += __shfl_xor(p1, 1);
                p0 += __shfl_xor(p0, 2);  p1 += __shfl_xor(p1, 2);
                p0 += __shfl_xor(p0, 4);  p1 += __shfl_xor(p1, 4);
                p0 += __shfl_xor(p0, 8);  p1 += __shfl_xor(p1, 8);
                if (l15 == 0) {
                    const int t = mt * 16 + l4 * 4 + r;
                    s_att[2 * w][t]     = p0 * (1.0f / 3.0f);
                    s_att[2 * w + 1][t] = p1 * (1.0f / 3.0f);
                }
            }
    }
    __syncthreads();

    // ---- softmax over t ----
    if (tid < NV) {
        float m = -1e30f;
        for (int t = 0; t < HIS; ++t) m = fmaxf(m, s_att[tid][t]);
        float ssum = 0.0f;
        for (int t = 0; t < HIS; ++t) {
            const float ex = expf(s_att[tid][t] - m);
            s_att[tid][t] = ex;
            ssum += ex;
        }
        const float inv = 1.0f / ssum;
        for (int t = 0; t < HIS; ++t) s_att[tid][t] *= inv;
        for (int t = HIS; t < 64; ++t) s_att[tid][t] = 0.0f;
    }
    __syncthreads();

    // ---- pass 2: vh GEMM -> PV ----
    #pragma unroll
    for (int mt = 0; mt < 4; ++mt)
        #pragma unroll
        for (int nt = 0; nt < 4; ++nt) acc[mt][nt] = (f32x4)0.0f;

    #pragma unroll 2
    for (int kk = 0; kk < 8; ++kk) {
        half8 afr[4];
        #pragma unroll
        for (int mt = 0; mt < 4; ++mt) {
            const int t = mt * 16 + l15;
            const int g = (kk * 4 + l4) ^ (t & 7);
            afr[mt] = encv[t * 32 + g];
        }
        #pragma unroll
        for (int nt = 0; nt < 4; ++nt) {
            const half8 bfr = *reinterpret_cast<const half8*>(
                WvP + ((size_t)((w * 4 + nt) * 8 + kk) * 64 + lane) * 8);
            #pragma unroll
            for (int mt = 0; mt < 4; ++mt)
                acc[mt][nt] = __builtin_amdgcn_mfma_f32_16x16x32_f16(afr[mt], bfr, acc[mt][nt], 0, 0, 0);
        }
    }

    {
        float bvb[4];
        #pragma unroll
        for (int nt = 0; nt < 4; ++nt) bvb[nt] = bv[w * 64 + nt * 16 + l15];
        float o0 = 0.f, o1 = 0.f, o2 = 0.f, o3 = 0.f;
        #pragma unroll
        for (int mt = 0; mt < 4; ++mt)
            #pragma unroll
            for (int r = 0; r < 4; ++r) {
                const int t = mt * 16 + l4 * 4 + r;
                const float a0 = s_att[2 * w][t];
                const float a1 = s_att[2 * w + 1][t];
                o0 += a0 * fmaxf(acc[mt][0][r] + bvb[0], 0.0f);
                o1 += a0 * fmaxf(acc[mt][1][r] + bvb[1], 0.0f);
                o2 += a1 * fmaxf(acc[mt][2][r] + bvb[2], 0.0f);
                o3 += a1 * fmaxf(acc[mt][3][r] + bvb[3], 0.0f);
            }
        o0 += __shfl_xor(o0, 16); o1 += __shfl_xor(o1, 16);
        o2 += __shfl_xor(o2, 16); o3 += __shfl_xor(o3, 16);
        o0 += __shfl_xor(o0, 32); o1 += __shfl_xor(o1, 32);
        o2 += __shfl_xor(o2, 32); o3 += __shfl_xor(o3, 32);
        if (lane < 16) {
            s_o[w * 64 +  0 + l15] = o0;
            s_o[w * 64 + 16 + l15] = o1;
            s_o[w * 64 + 32 + l15] = o2;
            s_o[w * 64 + 48 + l15] = o3;
        }
    }
    __syncthreads();

    // ---- out projection (coalesced interleaved weights) ----
    {
        const int e = tid;
        float acc2 = bout[e];
        #pragma unroll 4
        for (int j = 0; j < 32; ++j) {
            const half8 hv = *reinterpret_cast<const half8*>(&WoI[(j * EDIM + e) * 8]);
            const float4 o0 = *reinterpret_cast<const float4*>(&s_o[j * 8]);
            const float4 o1 = *reinterpret_cast<const float4*>(&s_o[j * 8 + 4]);
            acc2 += o0.x*(float)hv[0] + o0.y*(float)hv[1] + o0.z*(float)hv[2] + o0.w*(float)hv[3]
                  + o1.x*(float)hv[4] + o1.y*(float)hv[5] + o1.z*(float)hv[6] + o1.w*(float)hv[7];
        }
        out[bidx * EDIM + e] = fmaxf(acc2, 0.0f);
    }
}

// ---------------- fallback fused kernel (round-2 structure, new weight layout) ----------------
__global__ __launch_bounds__(256) void mha_mfma(
    const float* __restrict__ q,
    const float* __restrict__ kin,
    const float* __restrict__ bq,
    const float* __restrict__ bk,
    const float* __restrict__ bv,
    const float* __restrict__ bout,
    const float* __restrict__ Wenc,
    const char*  __restrict__ ws,
    float* __restrict__ out)
{
    const int tid  = threadIdx.x;
    const int bidx = blockIdx.x;
    const int b = bidx >> 6;
    const int n = bidx & 63;
    const int lane = tid & 63;
    const int w    = tid >> 6;
    const int l15  = lane & 15;
    const int l4   = lane >> 4;

    const HALF*  WkP = (const HALF*)(ws + WS_WKP);
    const HALF*  WvP = (const HALF*)(ws + WS_WVP);
    const HALF*  WqI = (const HALF*)(ws + WS_WQI);
    const HALF*  WoI = (const HALF*)(ws + WS_WOI);
    const float* PE  = (const float*)(ws + WS_PE);
    const int*  idxT = (const int*)(ws + WS_IDX);

    __shared__ __align__(16) float s_q[EDIM];
    __shared__ __align__(16) float s_qh[EDIM];
    __shared__ __align__(16) float s_neigh[HIS][12];
    __shared__ __align__(16) HALF  s_enc[64 * EDIM];
    __shared__ float s_att[NV][64];
    __shared__ __align__(16) float s_o[EDIM];

    s_q[tid] = q[bidx * EDIM + tid];
    __syncthreads();

    for (int i = tid; i < HIS * 12; i += 256) {
        const int t = i / 12;
        const int d = i - t * 12;
        float val = 0.0f;
        if (d < DKA) val = kin[((b * HIS + t) * NA + idxT[n * HIS + t]) * DKA + d];
        s_neigh[t][d] = val;
    }
    __syncthreads();

    {
        const int e = tid;
        float acc = bq[e];
        #pragma unroll 4
        for (int j = 0; j < 32; ++j) {
            const half8 hv = *reinterpret_cast<const half8*>(&WqI[(j * EDIM + e) * 8]);
            const float4 q0 = *reinterpret_cast<const float4*>(&s_q[j * 8]);
            const float4 q1 = *reinterpret_cast<const float4*>(&s_q[j * 8 + 4]);
            acc += q0.x*(float)hv[0] + q0.y*(float)hv[1] + q0.z*(float)hv[2] + q0.w*(float)hv[3]
                 + q1.x*(float)hv[4] + q1.y*(float)hv[5] + q1.z*(float)hv[6] + q1.w*(float)hv[7];
        }
        s_qh[e] = fmaxf(acc, 0.0f);

        float we[12];
        #pragma unroll
        for (int j = 0; j < 12; ++j) we[j] = (j < DKA) ? Wenc[j * EDIM + e] : 0.0f;

        #pragma unroll 2
        for (int t = 0; t < HIS; ++t) {
            const float4 n0 = *reinterpret_cast<const float4*>(&s_neigh[t][0]);
            const float4 n1 = *reinterpret_cast<const float4*>(&s_neigh[t][4]);
            const float4 n2 = *reinterpret_cast<const float4*>(&s_neigh[t][8]);
            float x = n0.x*we[0] + n0.y*we[1] + n0.z*we[2] + n0.w*we[3]
                    + n1.x*we[4] + n1.y*we[5] + n1.z*we[6] + n1.w*we[7]
                    + n2.x*we[8];
            x = 0.5f * x * (1.0f + erff(x * 0.70710678118654752f));
            const float v = x + PE[t * EDIM + e];
            s_enc[t * EDIM + (((e >> 3) ^ (t & 7)) << 3) + (e & 7)] = (HALF)v;
        }
        #pragma unroll
        for (int t = HIS; t < 64; ++t)
            s_enc[t * EDIM + (((e >> 3) ^ (t & 7)) << 3) + (e & 7)] = (HALF)0.0f;
    }
    __syncthreads();

    f32x4 ka[4][4], va[4][4];
    #pragma unroll
    for (int mt = 0; mt < 4; ++mt)
        #pragma unroll
        for (int nt = 0; nt < 4; ++nt) { ka[mt][nt] = (f32x4)0.0f; va[mt][nt] = (f32x4)0.0f; }

    #pragma unroll 2
    for (int kk = 0; kk < 8; ++kk) {
        half8 afr[4];
        #pragma unroll
        for (int mt = 0; mt < 4; ++mt) {
            const int t  = mt * 16 + l15;
            const int g  = ((kk * 4 + l4)) ^ (t & 7);
            afr[mt] = *reinterpret_cast<const half8*>(&s_enc[t * EDIM + g * 8]);
        }
        #pragma unroll
        for (int nt = 0; nt < 4; ++nt) {
            const size_t off = ((size_t)((w * 4 + nt) * 8 + kk) * 64 + lane) * 8;
            const half8 bkfr = *reinterpret_cast<const half8*>(WkP + off);
            const half8 bvfr = *reinterpret_cast<const half8*>(WvP + off);
            #pragma unroll
            for (int mt = 0; mt < 4; ++mt) {
                ka[mt][nt] = __builtin_amdgcn_mfma_f32_16x16x32_f16(afr[mt], bkfr, ka[mt][nt], 0, 0, 0);
                va[mt][nt] = __builtin_amdgcn_mfma_f32_16x16x32_f16(afr[mt], bvfr, va[mt][nt], 0, 0, 0);
            }
        }
    }

    {
        float qv[4], bkb[4];
        #pragma unroll
        for (int nt = 0; nt < 4; ++nt) {
            const int col = w * 64 + nt * 16 + l15;
            qv[nt]  = s_qh[col];
            bkb[nt] = bk[col];
        }
        #pragma unroll
        for (int mt = 0; mt < 4; ++mt)
            #pragma unroll
            for (int r = 0; r < 4; ++r) {
                float p0 = qv[0] * fmaxf(ka[mt][0][r] + bkb[0], 0.0f)
                         + qv[1] * fmaxf(ka[mt][1][r] + bkb[1], 0.0f);
                float p1 = qv[2] * fmaxf(ka[mt][2][r] + bkb[2], 0.0f)
                         + qv[3] * fmaxf(ka[mt][3][r] + bkb[3], 0.0f);
                p0 += __shfl_xor(p0, 1);  p1 += __shfl_xor(p1, 1);
                p0 += __shfl_xor(p0, 2);  p1 += __shfl_xor(p1, 2);
                p0 += __shfl_xor(p0, 4);  p1 += __shfl_xor(p1, 4);
                p0 += __shfl_xor(p0, 8);  p1 += __shfl_xor(p1, 8);
                if (l15 == 0) {
                    const int t = mt * 16 + l4 * 4 + r;
                    s_att[2 * w][t]     = p0 * (1.0f / 3.0f);
                    s_att[2 * w + 1][t] = p1 * (1.0f / 3.0f);
                }
            }
    }
    __syncthreads();

    if (tid < NV) {
        float m = -1e30f;
        for (int t = 0; t < HIS; ++t) m = fmaxf(m, s_att[tid][t]);
        float ssum = 0.0f;
        for (int t = 0; t < HIS; ++t) {
            const float ex = expf(s_att[tid][t] - m);
            s_att[tid][t] = ex;
            ssum += ex;
        }
        const float inv = 1.0f / ssum;
        for (int t = 0; t < HIS; ++t) s_att[tid][t] *= inv;
        for (int t = HIS; t < 64; ++t) s_att[tid][t] = 0.0f;
    }
    __syncthreads();

    {
        float bvb[4];
        #pragma unroll
        for (int nt = 0; nt < 4; ++nt) bvb[nt] = bv[w * 64 + nt * 16 + l15];
        float o0 = 0.f, o1 = 0.f, o2 = 0.f, o3 = 0.f;
        #pragma unroll
        for (int mt = 0; mt < 4; ++mt)
            #pragma unroll
            for (int r = 0; r < 4; ++r) {
                const int t = mt * 16 + l4 * 4 + r;
                const float a0 = s_att[2 * w][t];
                const float a1 = s_att[2 * w + 1][t];
                o0 += a0 * fmaxf(va[mt][0][r] + bvb[0], 0.0f);
                o1 += a0 * fmaxf(va[mt][1][r] + bvb[1], 0.0f);
                o2 += a1 * fmaxf(va[mt][2][r] + bvb[2], 0.0f);
                o3 += a1 * fmaxf(va[mt][3][r] + bvb[3], 0.0f);
            }
        o0 += __shfl_xor(o0, 16); o1 += __shfl_xor(o1, 16);
        o2 += __shfl_xor(o2, 16); o3 += __shfl_xor(o3, 16);
        o0 += __shfl_xor(o0, 32); o1 += __shfl_xor(o1, 32);
        o2 += __shfl_xor(o2, 32); o3 += __shfl_xor(o3, 32);
        if (lane < 16) {
            s_o[w * 64 +  0 + l15] = o0;
            s_o[w * 64 + 16 + l15] = o1;
            s_o[w * 64 + 32 + l15] = o2;
            s_o[w * 64 + 48 + l15] = o3;
        }
    }
    __syncthreads();

    {
        const int e = tid;
        float acc = bout[e];
        #pragma unroll 4
        for (int j = 0; j < 32; ++j) {
            const half8 hv = *reinterpret_cast<const half8*>(&WoI[(j * EDIM + e) * 8]);
            const float4 o0 = *reinterpret_cast<const float4*>(&s_o[j * 8]);
            const float4 o1 = *reinterpret_cast<const float4*>(&s_o[j * 8 + 4]);
            acc += o0.x*(float)hv[0] + o0.y*(float)hv[1] + o0.z*(float)hv[2] + o0.w*(float)hv[3]
                 + o1.x*(float)hv[4] + o1.y*(float)hv[5] + o1.z*(float)hv[6] + o1.w*(float)hv[7];
        }
        out[bidx * EDIM + e] = fmaxf(acc, 0.0f);
    }
}

extern "C" void kernel_launch(void* const* d_in, const int* in_sizes, int n_in,
                              void* d_out, int out_size, void* d_ws, size_t ws_size,
                              hipStream_t stream) {
    const float* q    = (const float*)d_in[0];
    const float* kin  = (const float*)d_in[1];
    const float* adjs = (const float*)d_in[2];
    const float* Wq   = (const float*)d_in[3];
    const float* bq   = (const float*)d_in[4];
    const float* Wk   = (const float*)d_in[5];
    const float* bk   = (const float*)d_in[6];
    const float* Wv   = (const float*)d_in[7];
    const float* bv   = (const float*)d_in[8];
    const float* Wout = (const float*)d_in[9];
    const float* bout = (const float*)d_in[10];
    const float* Wenc = (const float*)d_in[11];
    float* out = (float*)d_out;
    char* ws = (char*)d_ws;

    hipLaunchKernelGGL(pack_setup, dim3(256), dim3(256), 0, stream,
                       Wk, Wv, Wq, Wout, adjs, ws);

    if (ws_size >= WS_NEED) {
        hipLaunchKernelGGL(enc_kernel, dim3(NB * NA), dim3(256), 0, stream,
                           q, kin, bq, Wenc, ws, ws);
        hipLaunchKernelGGL(attn_kernel, dim3(NB * NA), dim3(256), 0, stream,
                           bk, bv, bout, ws, out);
    } else {
        hipLaunchKernelGGL(mha_mfma, dim3(NB * NA), dim3(256), 0, stream,
                           q, kin, bq, bk, bv, bout, Wenc, ws, out);
    }
}